// Round 1
// baseline (629.788 us; speedup 1.0000x reference)
//
#include <hip/hip_runtime.h>
#include <hip/hip_cooperative_groups.h>
#include <math.h>

namespace cg = cooperative_groups;

// SE layer: B=16, C=256, H=W=128. Only batch 0 is gated (reference uses s[0]).
#define HW    16384        // 128*128
#define CCH   256
#define HID   16
#define NBLK  1024         // 4 blocks/CU on 256 CUs -> cooperative residency safe
#define NTHR  256
#define BPC   (NBLK / CCH) // pool blocks per channel = 4

typedef float f4 __attribute__((ext_vector_type(4)));

// One fused cooperative kernel:
//  Phase 1: pooled partial sums of batch 0 (BPC blocks per channel).
//  Phase 2: block 0 runs the tiny MLP while ALL blocks copy batches 1..15
//           (the copy has no dependency on the gates -> MLP latency hidden).
//           Copy is nontemporal so batch 0 stays resident in L3 for phase 3.
//  Phase 3: all blocks scale batch 0 by the gates.
__global__ __launch_bounds__(NTHR, 4) void se_fused(
        const float* __restrict__ x,
        const float* __restrict__ w1, const float* __restrict__ b1,
        const float* __restrict__ w2, const float* __restrict__ b2,
        float* __restrict__ out, float* __restrict__ ws) {
    cg::grid_group grid = cg::this_grid();
    const int bid = blockIdx.x;
    const int t   = threadIdx.x;
    float* part = ws;           // NBLK partial channel sums (fully rewritten each run)
    float* svec = ws + NBLK;    // CCH sigmoid gates        (fully rewritten each run)

    // ---- Phase 1: partial sums of batch 0, channel = bid/BPC, quarter = bid%BPC ----
    {
        const int c = bid >> 2;            // bid / BPC
        const int q = bid & (BPC - 1);
        const f4* p = (const f4*)(x + (size_t)c * HW) + (size_t)q * (HW / 4 / BPC);
        float sum = 0.f;
        #pragma unroll
        for (int i = 0; i < (HW / 4 / BPC) / NTHR; ++i) {   // 4 iters of 256 threads
            f4 v = p[(size_t)i * NTHR + t];                 // normal load: keep in L3
            sum += (v.x + v.y) + (v.z + v.w);
        }
        #pragma unroll
        for (int off = 32; off > 0; off >>= 1)
            sum += __shfl_down(sum, off, 64);
        __shared__ float wsum[NTHR / 64];
        if ((t & 63) == 0) wsum[t >> 6] = sum;
        __syncthreads();
        if (t == 0) part[bid] = (wsum[0] + wsum[1]) + (wsum[2] + wsum[3]);
    }
    grid.sync();

    // ---- Phase 2: block 0 -> MLP; everyone -> copy batches 1..15 ----
    if (bid == 0) {
        __shared__ float ysh[CCH];
        __shared__ float h[HID];
        float acc0 = 0.f;
        #pragma unroll
        for (int k = 0; k < BPC; ++k) acc0 += part[t * BPC + k];
        ysh[t] = acc0 * (1.0f / (float)HW);
        __syncthreads();
        if (t < HID) {
            float acc = b1[t];
            const float* wr = w1 + t * CCH;
            #pragma unroll 8
            for (int c = 0; c < CCH; ++c) acc = fmaf(ysh[c], wr[c], acc);
            h[t] = fmaxf(acc, 0.f);
        }
        __syncthreads();
        float acc = b2[t];
        const float* wr2 = w2 + t * HID;
        #pragma unroll
        for (int j = 0; j < HID; ++j) acc = fmaf(h[j], wr2[j], acc);
        svec[t] = 1.0f / (1.0f + __expf(-acc));
    }
    {
        const size_t base4 = (size_t)CCH * (HW / 4);        // 1,048,576 float4 / batch
        const size_t n4    = 15 * base4;                    // batches 1..15
        const f4* __restrict__ xin = (const f4*)x + base4;
        f4* __restrict__ o = (f4*)out + base4;
        for (size_t i = (size_t)bid * NTHR + t; i < n4; i += (size_t)NBLK * NTHR) {
            f4 v = __builtin_nontemporal_load(xin + i);     // don't thrash L3
            __builtin_nontemporal_store(v, o + i);
        }
    }
    grid.sync();

    // ---- Phase 3: scale batch 0 by the gates (x[0] hopefully still in L3) ----
    {
        const size_t b0 = (size_t)CCH * (HW / 4);
        const f4* __restrict__ xin = (const f4*)x;
        f4* __restrict__ o = (f4*)out;
        for (size_t i = (size_t)bid * NTHR + t; i < b0; i += (size_t)NBLK * NTHR) {
            f4 v = xin[i];
            const float g = svec[i >> 12];   // 4096 float4 per channel -> i>>12
            v.x *= g; v.y *= g; v.z *= g; v.w *= g;
            __builtin_nontemporal_store(v, o + i);
        }
    }
}

extern "C" void kernel_launch(void* const* d_in, const int* in_sizes, int n_in,
                              void* d_out, int out_size, void* d_ws, size_t ws_size,
                              hipStream_t stream) {
    const float* x  = (const float*)d_in[0];
    const float* w1 = (const float*)d_in[1];
    const float* b1 = (const float*)d_in[2];
    const float* w2 = (const float*)d_in[3];
    const float* b2 = (const float*)d_in[4];
    float* out = (float*)d_out;
    float* ws  = (float*)d_ws;   // needs NBLK + CCH floats = 5 KiB

    void* args[] = {(void*)&x, (void*)&w1, (void*)&b1, (void*)&w2, (void*)&b2,
                    (void*)&out, (void*)&ws};
    hipLaunchCooperativeKernel((const void*)se_fused, dim3(NBLK), dim3(NTHR),
                               args, 0, stream);
}